// Round 4
// baseline (431.563 us; speedup 1.0000x reference)
//
#include <hip/hip_runtime.h>
#include <math.h>

#define NN 8192
#define FD 64
#define AD 8
#define H  32
#define CAP 128        // max neighbors stored per row; deg ~ Poisson(32), P(>128) ~ 1e-40
#define NENC (NN / 256)   // 32 encoder blocks, dispatched FIRST
#define NPAIR (NN / 2)    // 4096 scan blocks, each owns rows {p, NN-1-p}

typedef unsigned short u16;

// LDS layout for the merged kernel (floats)
#define OW1 0                 // (FD+AD)*H = 2304
#define OW2 2304              // H*H = 1024
#define OWG 3328              // H*H = 1024
#define OB1 4352              // H
#define OB2 4384              // H
#define SMEM_FLOATS 4416      // 17.25 KB -> 8 blocks/CU fits in 160 KB LDS

// ---------------------------------------------------------------------------
// Upper-triangle scan of one row r: columns (r+1)..NN-1.  Each nonzero (r,c)
// appends c to row r's list and r to row c's list (global atomic slot alloc;
// order within a list is irrelevant because aggregation is a sum).
// 2-deep software pipeline keeps 2 KB/wave in flight.
// ---------------------------------------------------------------------------
__device__ __forceinline__ void scan_row(const float4* __restrict__ arow, const int r,
                                         int* __restrict__ cnt, u16* __restrict__ nbr) {
    int i4 = ((r + 1) >> 2) + (int)threadIdx.x;
    if (i4 >= NN / 4) return;
    float4 v = arow[i4];
    for (;;) {
        const int nx = i4 + 256;
        const bool more = (nx < NN / 4);
        float4 vn;
        if (more) vn = arow[nx];

        const int base = i4 * 4;
        if (v.x != 0.0f && base > r) {
            const int s = atomicAdd(&cnt[r], 1);
            if (s < CAP) nbr[(size_t)r * CAP + s] = (u16)base;
            const int s2 = atomicAdd(&cnt[base], 1);
            if (s2 < CAP) nbr[(size_t)base * CAP + s2] = (u16)r;
        }
        if (v.y != 0.0f && base + 1 > r) {
            const int c = base + 1;
            const int s = atomicAdd(&cnt[r], 1);
            if (s < CAP) nbr[(size_t)r * CAP + s] = (u16)c;
            const int s2 = atomicAdd(&cnt[c], 1);
            if (s2 < CAP) nbr[(size_t)c * CAP + s2] = (u16)r;
        }
        if (v.z != 0.0f && base + 2 > r) {
            const int c = base + 2;
            const int s = atomicAdd(&cnt[r], 1);
            if (s < CAP) nbr[(size_t)r * CAP + s] = (u16)c;
            const int s2 = atomicAdd(&cnt[c], 1);
            if (s2 < CAP) nbr[(size_t)c * CAP + s2] = (u16)r;
        }
        if (v.w != 0.0f && base + 3 > r) {
            const int c = base + 3;
            const int s = atomicAdd(&cnt[r], 1);
            if (s < CAP) nbr[(size_t)r * CAP + s] = (u16)c;
            const int s2 = atomicAdd(&cnt[c], 1);
            if (s2 < CAP) nbr[(size_t)c * CAP + s2] = (u16)r;
        }

        if (!more) break;
        v = vn; i4 = nx;
    }
}

// ---------------------------------------------------------------------------
// Kernel 1 (merged): blocks [0, NENC) run the encoder (dispatched first, hide
// under the BW-bound scan); blocks [NENC, NENC+NPAIR) scan rows {p, NN-1-p}
// of the upper triangle (uniform ~32 KB per block).  Encoder emits UNSCALED
// T = X@Wg (dinv folded into the aggregation fma later), so paths are
// independent.  launch_bounds(256,8) keeps VGPR<=64 so scan blocks reach
// 32 waves/CU (encoder may spill slightly; it is ~2us on 32 blocks).
// ---------------------------------------------------------------------------
__global__ __launch_bounds__(256, 8) void pre_k(const float4* __restrict__ adj,
                                                const float* __restrict__ feat,
                                                const float* __restrict__ act,
                                                const float* __restrict__ We1,
                                                const float* __restrict__ be1,
                                                const float* __restrict__ We2,
                                                const float* __restrict__ be2,
                                                const float* __restrict__ Wg,
                                                u16* __restrict__ nbr,
                                                int* __restrict__ cnt,
                                                float* __restrict__ X,
                                                float* __restrict__ T) {
    __shared__ float smem[SMEM_FLOATS];

    if (blockIdx.x >= NENC) {
        const int p = blockIdx.x - NENC;
        scan_row(adj + (size_t)p * (NN / 4), p, cnt, nbr);
        const int r2 = NN - 1 - p;
        scan_row(adj + (size_t)r2 * (NN / 4), r2, cnt, nbr);
    } else {
        // ----------------- encoder path: thread-per-row ---------------------
        for (int i = threadIdx.x; i < (FD + AD) * H; i += 256) smem[OW1 + i] = We1[i];
        for (int i = threadIdx.x; i < H * H; i += 256) {
            smem[OW2 + i] = We2[i];
            smem[OWG + i] = Wg[i];
        }
        if (threadIdx.x < H) {
            smem[OB1 + threadIdx.x] = be1[threadIdx.x];
            smem[OB2 + threadIdx.x] = be2[threadIdx.x];
        }
        __syncthreads();

        const int row = blockIdx.x * 256 + threadIdx.x;

        float h1[H];
#pragma unroll
        for (int o = 0; o < H; ++o) h1[o] = smem[OB1 + o];

        // consume features float4-at-a-time (no in[72] array -> low VGPR)
        const float4* f4 = (const float4*)(feat + (size_t)row * FD);
#pragma unroll
        for (int i = 0; i < FD / 4; ++i) {
            const float4 v = f4[i];
            const int b = 4 * i;
#pragma unroll
            for (int o = 0; o < H; ++o) h1[o] = fmaf(v.x, smem[OW1 + (b + 0) * H + o], h1[o]);
#pragma unroll
            for (int o = 0; o < H; ++o) h1[o] = fmaf(v.y, smem[OW1 + (b + 1) * H + o], h1[o]);
#pragma unroll
            for (int o = 0; o < H; ++o) h1[o] = fmaf(v.z, smem[OW1 + (b + 2) * H + o], h1[o]);
#pragma unroll
            for (int o = 0; o < H; ++o) h1[o] = fmaf(v.w, smem[OW1 + (b + 3) * H + o], h1[o]);
        }
        const float4* a4 = (const float4*)(act + (size_t)row * AD);
#pragma unroll
        for (int i = 0; i < AD / 4; ++i) {
            const float4 v = a4[i];
            const int b = FD + 4 * i;
#pragma unroll
            for (int o = 0; o < H; ++o) h1[o] = fmaf(v.x, smem[OW1 + (b + 0) * H + o], h1[o]);
#pragma unroll
            for (int o = 0; o < H; ++o) h1[o] = fmaf(v.y, smem[OW1 + (b + 1) * H + o], h1[o]);
#pragma unroll
            for (int o = 0; o < H; ++o) h1[o] = fmaf(v.z, smem[OW1 + (b + 2) * H + o], h1[o]);
#pragma unroll
            for (int o = 0; o < H; ++o) h1[o] = fmaf(v.w, smem[OW1 + (b + 3) * H + o], h1[o]);
        }
#pragma unroll
        for (int o = 0; o < H; ++o) h1[o] = fmaxf(h1[o], 0.0f);

        float h2[H];
#pragma unroll
        for (int o = 0; o < H; ++o) h2[o] = smem[OB2 + o];
#pragma unroll
        for (int i = 0; i < H; ++i) {
            const float xi = h1[i];
#pragma unroll
            for (int o = 0; o < H; ++o) h2[o] = fmaf(xi, smem[OW2 + i * H + o], h2[o]);
        }
#pragma unroll
        for (int o = 0; o < H; ++o) h2[o] = fmaxf(h2[o], 0.0f);

        float* Xr = X + (size_t)row * H;
#pragma unroll
        for (int o = 0; o < H; o += 4)
            *(float4*)(Xr + o) = make_float4(h2[o], h2[o + 1], h2[o + 2], h2[o + 3]);

        // t reuses h1's registers (h1 dead after relu->h2)
#pragma unroll
        for (int o = 0; o < H; ++o) h1[o] = 0.0f;
#pragma unroll
        for (int i = 0; i < H; ++i) {
            const float xi = h2[i];
#pragma unroll
            for (int o = 0; o < H; ++o) h1[o] = fmaf(xi, smem[OWG + i * H + o], h1[o]);
        }
        float* Tr = T + (size_t)row * H;
#pragma unroll
        for (int o = 0; o < H; o += 4)
            *(float4*)(Tr + o) = make_float4(h1[o], h1[o + 1], h1[o + 2], h1[o + 3]);
    }
}

// ---------------------------------------------------------------------------
// Kernel 2: aggregation + heads.  One thread per row, 64-thread blocks.
// di = 1/sqrt(cnt[row]+1) recomputed on the fly (dinv array eliminated).
// acc = T[row]*di + sum_j T[j]*dj;  edge loop unrolled x4 for MLP latency.
// ---------------------------------------------------------------------------
__global__ __launch_bounds__(64) void fin_k(const float* __restrict__ T,
                                            const float* __restrict__ X,
                                            const u16* __restrict__ nbr,
                                            const int* __restrict__ cnt,
                                            const float* __restrict__ bg,
                                            const float* __restrict__ Wgd,
                                            const float* __restrict__ bgd,
                                            const float* __restrict__ Wp1,
                                            const float* __restrict__ bp1,
                                            const float* __restrict__ Wp2,
                                            const float* __restrict__ bp2,
                                            const float* __restrict__ Wv,
                                            const float* __restrict__ bv,
                                            float* __restrict__ out) {
    __shared__ float sbg[H];
    __shared__ float sWgd[H * H];
    __shared__ float sbgd[H];
    __shared__ float sWp1[2 * H * H];
    __shared__ float sbp1[H];
    __shared__ float sWp2[H * H];
    __shared__ float sbp2[H];
    __shared__ float sWv[H];
    __shared__ float sbv;
    for (int i = threadIdx.x; i < H * H; i += 64) { sWgd[i] = Wgd[i]; sWp2[i] = Wp2[i]; }
    for (int i = threadIdx.x; i < 2 * H * H; i += 64) sWp1[i] = Wp1[i];
    if (threadIdx.x < H) {
        sbg[threadIdx.x]  = bg[threadIdx.x];
        sbgd[threadIdx.x] = bgd[threadIdx.x];
        sbp1[threadIdx.x] = bp1[threadIdx.x];
        sbp2[threadIdx.x] = bp2[threadIdx.x];
        sWv[threadIdx.x]  = Wv[threadIdx.x];
    }
    if (threadIdx.x == 0) sbv = bv[0];
    __syncthreads();

    const int row = blockIdx.x * 64 + threadIdx.x;
    const int n_raw = cnt[row];
    const int n = (n_raw < CAP) ? n_raw : CAP;
    const float di = 1.0f / sqrtf((float)n_raw + 1.0f);

    float acc[H];
    const float4* Tr = (const float4*)(T + (size_t)row * H);
#pragma unroll
    for (int q = 0; q < H / 4; ++q) {
        float4 v = Tr[q];
        acc[4 * q]     = v.x * di; acc[4 * q + 1] = v.y * di;
        acc[4 * q + 2] = v.z * di; acc[4 * q + 3] = v.w * di;
    }

    const u16* myn = nbr + (size_t)row * CAP;
    int e = 0;
    for (; e + 4 <= n; e += 4) {
        const ushort4 ii = *(const ushort4*)(myn + e);   // 8B-aligned (e%4==0)
        const int j0 = ii.x, j1 = ii.y, j2 = ii.z, j3 = ii.w;
        const int c0 = cnt[j0], c1 = cnt[j1], c2 = cnt[j2], c3 = cnt[j3];
        const float d0 = 1.0f / sqrtf((float)c0 + 1.0f);
        const float d1 = 1.0f / sqrtf((float)c1 + 1.0f);
        const float d2 = 1.0f / sqrtf((float)c2 + 1.0f);
        const float d3 = 1.0f / sqrtf((float)c3 + 1.0f);
        const float4* T0 = (const float4*)(T + (size_t)j0 * H);
        const float4* T1 = (const float4*)(T + (size_t)j1 * H);
        const float4* T2 = (const float4*)(T + (size_t)j2 * H);
        const float4* T3 = (const float4*)(T + (size_t)j3 * H);
#pragma unroll
        for (int q = 0; q < H / 4; ++q) {
            const float4 a = T0[q], b = T1[q], c = T2[q], d = T3[q];
            acc[4 * q]     = fmaf(a.x, d0, acc[4 * q]);
            acc[4 * q + 1] = fmaf(a.y, d0, acc[4 * q + 1]);
            acc[4 * q + 2] = fmaf(a.z, d0, acc[4 * q + 2]);
            acc[4 * q + 3] = fmaf(a.w, d0, acc[4 * q + 3]);
            acc[4 * q]     = fmaf(b.x, d1, acc[4 * q]);
            acc[4 * q + 1] = fmaf(b.y, d1, acc[4 * q + 1]);
            acc[4 * q + 2] = fmaf(b.z, d1, acc[4 * q + 2]);
            acc[4 * q + 3] = fmaf(b.w, d1, acc[4 * q + 3]);
            acc[4 * q]     = fmaf(c.x, d2, acc[4 * q]);
            acc[4 * q + 1] = fmaf(c.y, d2, acc[4 * q + 1]);
            acc[4 * q + 2] = fmaf(c.z, d2, acc[4 * q + 2]);
            acc[4 * q + 3] = fmaf(c.w, d2, acc[4 * q + 3]);
            acc[4 * q]     = fmaf(d.x, d3, acc[4 * q]);
            acc[4 * q + 1] = fmaf(d.y, d3, acc[4 * q + 1]);
            acc[4 * q + 2] = fmaf(d.z, d3, acc[4 * q + 2]);
            acc[4 * q + 3] = fmaf(d.w, d3, acc[4 * q + 3]);
        }
    }
    for (; e < n; ++e) {
        const int j = myn[e];
        const int cj = cnt[j];
        const float dj = 1.0f / sqrtf((float)cj + 1.0f);
        const float4* Tj = (const float4*)(T + (size_t)j * H);
#pragma unroll
        for (int q = 0; q < H / 4; ++q) {
            const float4 v = Tj[q];
            acc[4 * q]     = fmaf(v.x, dj, acc[4 * q]);
            acc[4 * q + 1] = fmaf(v.y, dj, acc[4 * q + 1]);
            acc[4 * q + 2] = fmaf(v.z, dj, acc[4 * q + 2]);
            acc[4 * q + 3] = fmaf(v.w, dj, acc[4 * q + 3]);
        }
    }

    float xg[H];
#pragma unroll
    for (int k = 0; k < H; ++k) xg[k] = fmaxf(fmaf(acc[k], di, sbg[k]), 0.0f);

    float xg2[H];
#pragma unroll
    for (int o = 0; o < H; ++o) xg2[o] = sbgd[o];
#pragma unroll
    for (int k = 0; k < H; ++k) {
        const float xk = xg[k];
#pragma unroll
        for (int o = 0; o < H; ++o) xg2[o] = fmaf(xk, sWgd[k * H + o], xg2[o]);
    }
#pragma unroll
    for (int o = 0; o < H; ++o) xg2[o] = fmaxf(xg2[o], 0.0f);

    float x[H];
    const float4* Xr = (const float4*)(X + (size_t)row * H);
#pragma unroll
    for (int q = 0; q < H / 4; ++q) {
        float4 v = Xr[q];
        x[4 * q] = v.x; x[4 * q + 1] = v.y; x[4 * q + 2] = v.z; x[4 * q + 3] = v.w;
    }

    float p1[H];
#pragma unroll
    for (int o = 0; o < H; ++o) p1[o] = sbp1[o];
#pragma unroll
    for (int k = 0; k < H; ++k) {
        const float xk = xg2[k];
#pragma unroll
        for (int o = 0; o < H; ++o) p1[o] = fmaf(xk, sWp1[k * H + o], p1[o]);
    }
#pragma unroll
    for (int k = 0; k < H; ++k) {
        const float xk = x[k];
#pragma unroll
        for (int o = 0; o < H; ++o) p1[o] = fmaf(xk, sWp1[(H + k) * H + o], p1[o]);
    }
#pragma unroll
    for (int o = 0; o < H; ++o) p1[o] = fmaxf(p1[o], 0.0f);

    float p2[H];
#pragma unroll
    for (int o = 0; o < H; ++o) p2[o] = sbp2[o];
#pragma unroll
    for (int k = 0; k < H; ++k) {
        const float xk = p1[k];
#pragma unroll
        for (int o = 0; o < H; ++o) p2[o] = fmaf(xk, sWp2[k * H + o], p2[o]);
    }

    float v = sbv;
#pragma unroll
    for (int k = 0; k < H; ++k) v = fmaf(fmaxf(p2[k], 0.0f), sWv[k], v);

    out[row] = v;
}

// ---------------------------------------------------------------------------
extern "C" void kernel_launch(void* const* d_in, const int* in_sizes, int n_in,
                              void* d_out, int out_size, void* d_ws, size_t ws_size,
                              hipStream_t stream) {
    (void)in_sizes; (void)n_in; (void)out_size; (void)ws_size;

    const float* feat = (const float*)d_in[0];
    const float* adj  = (const float*)d_in[1];
    /* d_in[2] = mask, unused */
    const float* act  = (const float*)d_in[3];
    const float* We1  = (const float*)d_in[4];
    const float* be1  = (const float*)d_in[5];
    const float* We2  = (const float*)d_in[6];
    const float* be2  = (const float*)d_in[7];
    const float* Wg   = (const float*)d_in[8];
    const float* bg   = (const float*)d_in[9];
    const float* Wgd  = (const float*)d_in[10];
    const float* bgd  = (const float*)d_in[11];
    const float* Wp1  = (const float*)d_in[12];
    const float* bp1  = (const float*)d_in[13];
    const float* Wp2  = (const float*)d_in[14];
    const float* bp2  = (const float*)d_in[15];
    const float* Wv   = (const float*)d_in[16];
    const float* bv   = (const float*)d_in[17];

    // workspace layout (16B-aligned chunks)
    char* ws = (char*)d_ws;
    u16*   nbr  = (u16*)ws;                                    // 8192*128*2  = 2 MiB
    char*  p    = ws + (size_t)NN * CAP * sizeof(u16);
    int*   cnt  = (int*)p;            p += (size_t)NN * 4;     // 32 KiB
    float* X    = (float*)p;          p += (size_t)NN * H * 4; // 1 MiB
    float* T    = (float*)p;                                   // 1 MiB (unscaled X@Wg)

    float* out = (float*)d_out;

    hipMemsetAsync(cnt, 0, (size_t)NN * sizeof(int), stream);  // atomic counters
    pre_k<<<NENC + NPAIR, 256, 0, stream>>>((const float4*)adj, feat, act,
                                            We1, be1, We2, be2, Wg,
                                            nbr, cnt, X, T);
    fin_k<<<NN / 64, 64, 0, stream>>>(T, X, nbr, cnt, bg, Wgd, bgd,
                                      Wp1, bp1, Wp2, bp2, Wv, bv, out);
}

// Round 6
// 430.179 us; speedup vs baseline: 1.0032x; 1.0032x over previous
//
#include <hip/hip_runtime.h>
#include <math.h>

#define NN 8192
#define FD 64
#define AD 8
#define H  32
#define CAP 128        // per-direction list capacity; deg/2 ~ Poisson(16), P(>128) ~ 0
#define NENC (NN / 256)   // 32 encoder blocks, dispatched FIRST
#define NPAIR (NN / 2)    // 4096 scan blocks, each owns rows {p, NN-1-p}

typedef unsigned short u16;

// LDS layout for the merged kernel (floats)
#define OW1 0                 // (FD+AD)*H = 2304
#define OW2 2304              // H*H = 1024
#define OWG 3328              // H*H = 1024
#define OB1 4352              // H
#define OB2 4384              // H
#define SMEM_FLOATS 4416      // 17.25 KB

// ---------------------------------------------------------------------------
// Kernel 1 (merged): blocks [0,NENC) = encoder (dispatched first, hides under
// the BW-bound scan).  Blocks [NENC, NENC+NPAIR): upper-triangle scan of rows
// {p, q=NN-1-p} — combined segment is a uniform ~32KB.  All ~9 float4 loads
// are issued upfront (8-deep MLP, the R3 pipeline).  For each nonzero (r,c),
// c>r: append c to nbrU[r] via LDS counter (no global contention) and r to
// nbrL[c] via one global atomic.
// ---------------------------------------------------------------------------
__global__ __launch_bounds__(256, 4) void pre_k(const float4* __restrict__ adj,
                                                const float* __restrict__ feat,
                                                const float* __restrict__ act,
                                                const float* __restrict__ We1,
                                                const float* __restrict__ be1,
                                                const float* __restrict__ We2,
                                                const float* __restrict__ be2,
                                                const float* __restrict__ Wg,
                                                u16* __restrict__ nbrU,
                                                u16* __restrict__ nbrL,
                                                int* __restrict__ cntU,
                                                int* __restrict__ cntL,
                                                float* __restrict__ X,
                                                float* __restrict__ T) {
    __shared__ float smem[SMEM_FLOATS];
    __shared__ int sPQ[2];

    if (blockIdx.x >= NENC) {
        // ----------------- triangle scan path -------------------------------
        const int p  = blockIdx.x - NENC;
        const int q  = NN - 1 - p;
        const int s0 = (p + 1) >> 2;      // first float4 of row p's upper seg
        const int l0 = NN / 4 - s0;
        const int s1 = (q + 1) >> 2;
        const int l1 = NN / 4 - s1;
        const int total = l0 + l1;        // 2048..2049

        if (threadIdx.x == 0) { sPQ[0] = 0; sPQ[1] = 0; }
        __syncthreads();

        const int tid = (int)threadIdx.x;

        // issue all loads upfront (up to 9 outstanding 1KB wave-loads)
        float4 v[9];
#pragma unroll
        for (int s = 0; s < 9; ++s) {
            const int vi = s * 256 + tid;
            if (vi < total) {
                const bool inP = vi < l0;
                const int r  = inP ? p : q;
                const int i4 = inP ? (s0 + vi) : (s1 + (vi - l0));
                v[s] = adj[(size_t)r * (NN / 4) + i4];
            }
        }

#pragma unroll
        for (int s = 0; s < 9; ++s) {
            const int vi = s * 256 + tid;
            if (vi >= total) continue;
            const bool inP = vi < l0;
            const int r    = inP ? p : q;
            const int idx  = inP ? 0 : 1;
            const int i4   = inP ? (s0 + vi) : (s1 + (vi - l0));
            const int base = i4 * 4;
            const float4 vv = v[s];
#pragma unroll
            for (int k = 0; k < 4; ++k) {
                const float val = (k == 0) ? vv.x : (k == 1) ? vv.y : (k == 2) ? vv.z : vv.w;
                const int c = base + k;
                if (val != 0.0f && c > r) {
                    const int sl = atomicAdd(&sPQ[idx], 1);        // LDS atomic
                    if (sl < CAP) nbrU[(size_t)r * CAP + sl] = (u16)c;
                    const int s2 = atomicAdd(&cntL[c], 1);         // global atomic
                    if (s2 < CAP) nbrL[(size_t)c * CAP + s2] = (u16)r;
                }
            }
        }
        __syncthreads();
        if (threadIdx.x == 0) {
            cntU[p] = sPQ[0];
            cntU[q] = sPQ[1];
        }
    } else {
        // ----------------- encoder path: thread-per-row ---------------------
        for (int i = threadIdx.x; i < (FD + AD) * H; i += 256) smem[OW1 + i] = We1[i];
        for (int i = threadIdx.x; i < H * H; i += 256) {
            smem[OW2 + i] = We2[i];
            smem[OWG + i] = Wg[i];
        }
        if (threadIdx.x < H) {
            smem[OB1 + threadIdx.x] = be1[threadIdx.x];
            smem[OB2 + threadIdx.x] = be2[threadIdx.x];
        }
        __syncthreads();

        const int row = blockIdx.x * 256 + threadIdx.x;

        float h1[H];
#pragma unroll
        for (int o = 0; o < H; ++o) h1[o] = smem[OB1 + o];

        const float4* f4 = (const float4*)(feat + (size_t)row * FD);
#pragma unroll
        for (int i = 0; i < FD / 4; ++i) {
            const float4 v = f4[i];
            const int b = 4 * i;
#pragma unroll
            for (int o = 0; o < H; ++o) h1[o] = fmaf(v.x, smem[OW1 + (b + 0) * H + o], h1[o]);
#pragma unroll
            for (int o = 0; o < H; ++o) h1[o] = fmaf(v.y, smem[OW1 + (b + 1) * H + o], h1[o]);
#pragma unroll
            for (int o = 0; o < H; ++o) h1[o] = fmaf(v.z, smem[OW1 + (b + 2) * H + o], h1[o]);
#pragma unroll
            for (int o = 0; o < H; ++o) h1[o] = fmaf(v.w, smem[OW1 + (b + 3) * H + o], h1[o]);
        }
        const float4* a4 = (const float4*)(act + (size_t)row * AD);
#pragma unroll
        for (int i = 0; i < AD / 4; ++i) {
            const float4 v = a4[i];
            const int b = FD + 4 * i;
#pragma unroll
            for (int o = 0; o < H; ++o) h1[o] = fmaf(v.x, smem[OW1 + (b + 0) * H + o], h1[o]);
#pragma unroll
            for (int o = 0; o < H; ++o) h1[o] = fmaf(v.y, smem[OW1 + (b + 1) * H + o], h1[o]);
#pragma unroll
            for (int o = 0; o < H; ++o) h1[o] = fmaf(v.z, smem[OW1 + (b + 2) * H + o], h1[o]);
#pragma unroll
            for (int o = 0; o < H; ++o) h1[o] = fmaf(v.w, smem[OW1 + (b + 3) * H + o], h1[o]);
        }
#pragma unroll
        for (int o = 0; o < H; ++o) h1[o] = fmaxf(h1[o], 0.0f);

        float h2[H];
#pragma unroll
        for (int o = 0; o < H; ++o) h2[o] = smem[OB2 + o];
#pragma unroll
        for (int i = 0; i < H; ++i) {
            const float xi = h1[i];
#pragma unroll
            for (int o = 0; o < H; ++o) h2[o] = fmaf(xi, smem[OW2 + i * H + o], h2[o]);
        }
#pragma unroll
        for (int o = 0; o < H; ++o) h2[o] = fmaxf(h2[o], 0.0f);

        float* Xr = X + (size_t)row * H;
#pragma unroll
        for (int o = 0; o < H; o += 4)
            *(float4*)(Xr + o) = make_float4(h2[o], h2[o + 1], h2[o + 2], h2[o + 3]);

        // t reuses h1 (dead after relu->h2)
#pragma unroll
        for (int o = 0; o < H; ++o) h1[o] = 0.0f;
#pragma unroll
        for (int i = 0; i < H; ++i) {
            const float xi = h2[i];
#pragma unroll
            for (int o = 0; o < H; ++o) h1[o] = fmaf(xi, smem[OWG + i * H + o], h1[o]);
        }
        float* Tr = T + (size_t)row * H;
#pragma unroll
        for (int o = 0; o < H; o += 4)
            *(float4*)(Tr + o) = make_float4(h1[o], h1[o + 1], h1[o + 2], h1[o + 3]);
    }
}

// ---------------------------------------------------------------------------
// Per-list gather: acc += sum_j T[j] * rsqrt(deg_j + 1), x4 unrolled.
// ---------------------------------------------------------------------------
__device__ __forceinline__ void gather_list(const float* __restrict__ T,
                                            const u16* __restrict__ list, const int n,
                                            const int* __restrict__ cntU,
                                            const int* __restrict__ cntL,
                                            float acc[H]) {
    int e = 0;
    for (; e + 4 <= n; e += 4) {
        const ushort4 ii = *(const ushort4*)(list + e);   // 8B-aligned (e%4==0, base 256B)
        const int j0 = ii.x, j1 = ii.y, j2 = ii.z, j3 = ii.w;
        const float d0 = 1.0f / sqrtf((float)(cntU[j0] + cntL[j0]) + 1.0f);
        const float d1 = 1.0f / sqrtf((float)(cntU[j1] + cntL[j1]) + 1.0f);
        const float d2 = 1.0f / sqrtf((float)(cntU[j2] + cntL[j2]) + 1.0f);
        const float d3 = 1.0f / sqrtf((float)(cntU[j3] + cntL[j3]) + 1.0f);
        const float4* T0 = (const float4*)(T + (size_t)j0 * H);
        const float4* T1 = (const float4*)(T + (size_t)j1 * H);
        const float4* T2 = (const float4*)(T + (size_t)j2 * H);
        const float4* T3 = (const float4*)(T + (size_t)j3 * H);
#pragma unroll
        for (int q = 0; q < H / 4; ++q) {
            const float4 a = T0[q], b = T1[q], c = T2[q], d = T3[q];
            acc[4 * q]     = fmaf(a.x, d0, acc[4 * q]);
            acc[4 * q + 1] = fmaf(a.y, d0, acc[4 * q + 1]);
            acc[4 * q + 2] = fmaf(a.z, d0, acc[4 * q + 2]);
            acc[4 * q + 3] = fmaf(a.w, d0, acc[4 * q + 3]);
            acc[4 * q]     = fmaf(b.x, d1, acc[4 * q]);
            acc[4 * q + 1] = fmaf(b.y, d1, acc[4 * q + 1]);
            acc[4 * q + 2] = fmaf(b.z, d1, acc[4 * q + 2]);
            acc[4 * q + 3] = fmaf(b.w, d1, acc[4 * q + 3]);
            acc[4 * q]     = fmaf(c.x, d2, acc[4 * q]);
            acc[4 * q + 1] = fmaf(c.y, d2, acc[4 * q + 1]);
            acc[4 * q + 2] = fmaf(c.z, d2, acc[4 * q + 2]);
            acc[4 * q + 3] = fmaf(c.w, d2, acc[4 * q + 3]);
            acc[4 * q]     = fmaf(d.x, d3, acc[4 * q]);
            acc[4 * q + 1] = fmaf(d.y, d3, acc[4 * q + 1]);
            acc[4 * q + 2] = fmaf(d.z, d3, acc[4 * q + 2]);
            acc[4 * q + 3] = fmaf(d.w, d3, acc[4 * q + 3]);
        }
    }
    for (; e < n; ++e) {
        const int j = list[e];
        const float dj = 1.0f / sqrtf((float)(cntU[j] + cntL[j]) + 1.0f);
        const float4* Tj = (const float4*)(T + (size_t)j * H);
#pragma unroll
        for (int q = 0; q < H / 4; ++q) {
            const float4 v = Tj[q];
            acc[4 * q]     = fmaf(v.x, dj, acc[4 * q]);
            acc[4 * q + 1] = fmaf(v.y, dj, acc[4 * q + 1]);
            acc[4 * q + 2] = fmaf(v.z, dj, acc[4 * q + 2]);
            acc[4 * q + 3] = fmaf(v.w, dj, acc[4 * q + 3]);
        }
    }
}

// ---------------------------------------------------------------------------
// Kernel 2: aggregation + heads.  One thread per row, 64-thread blocks.
// ---------------------------------------------------------------------------
__global__ __launch_bounds__(64) void fin_k(const float* __restrict__ T,
                                            const float* __restrict__ X,
                                            const u16* __restrict__ nbrU,
                                            const u16* __restrict__ nbrL,
                                            const int* __restrict__ cntU,
                                            const int* __restrict__ cntL,
                                            const float* __restrict__ bg,
                                            const float* __restrict__ Wgd,
                                            const float* __restrict__ bgd,
                                            const float* __restrict__ Wp1,
                                            const float* __restrict__ bp1,
                                            const float* __restrict__ Wp2,
                                            const float* __restrict__ bp2,
                                            const float* __restrict__ Wv,
                                            const float* __restrict__ bv,
                                            float* __restrict__ out) {
    __shared__ float sbg[H];
    __shared__ float sWgd[H * H];
    __shared__ float sbgd[H];
    __shared__ float sWp1[2 * H * H];
    __shared__ float sbp1[H];
    __shared__ float sWp2[H * H];
    __shared__ float sbp2[H];
    __shared__ float sWv[H];
    __shared__ float sbv;
    for (int i = threadIdx.x; i < H * H; i += 64) { sWgd[i] = Wgd[i]; sWp2[i] = Wp2[i]; }
    for (int i = threadIdx.x; i < 2 * H * H; i += 64) sWp1[i] = Wp1[i];
    if (threadIdx.x < H) {
        sbg[threadIdx.x]  = bg[threadIdx.x];
        sbgd[threadIdx.x] = bgd[threadIdx.x];
        sbp1[threadIdx.x] = bp1[threadIdx.x];
        sbp2[threadIdx.x] = bp2[threadIdx.x];
        sWv[threadIdx.x]  = Wv[threadIdx.x];
    }
    if (threadIdx.x == 0) sbv = bv[0];
    __syncthreads();

    const int row = blockIdx.x * 64 + threadIdx.x;
    const int cu = cntU[row], cl = cntL[row];
    const int nu = (cu < CAP) ? cu : CAP;
    const int nl = (cl < CAP) ? cl : CAP;
    const float di = 1.0f / sqrtf((float)(cu + cl) + 1.0f);

    float acc[H];
    const float4* Tr = (const float4*)(T + (size_t)row * H);
#pragma unroll
    for (int q = 0; q < H / 4; ++q) {
        float4 v = Tr[q];
        acc[4 * q]     = v.x * di; acc[4 * q + 1] = v.y * di;
        acc[4 * q + 2] = v.z * di; acc[4 * q + 3] = v.w * di;
    }

    gather_list(T, nbrU + (size_t)row * CAP, nu, cntU, cntL, acc);
    gather_list(T, nbrL + (size_t)row * CAP, nl, cntU, cntL, acc);

    float xg[H];
#pragma unroll
    for (int k = 0; k < H; ++k) xg[k] = fmaxf(fmaf(acc[k], di, sbg[k]), 0.0f);

    float xg2[H];
#pragma unroll
    for (int o = 0; o < H; ++o) xg2[o] = sbgd[o];
#pragma unroll
    for (int k = 0; k < H; ++k) {
        const float xk = xg[k];
#pragma unroll
        for (int o = 0; o < H; ++o) xg2[o] = fmaf(xk, sWgd[k * H + o], xg2[o]);
    }
#pragma unroll
    for (int o = 0; o < H; ++o) xg2[o] = fmaxf(xg2[o], 0.0f);

    float x[H];
    const float4* Xr = (const float4*)(X + (size_t)row * H);
#pragma unroll
    for (int q = 0; q < H / 4; ++q) {
        float4 v = Xr[q];
        x[4 * q] = v.x; x[4 * q + 1] = v.y; x[4 * q + 2] = v.z; x[4 * q + 3] = v.w;
    }

    float p1[H];
#pragma unroll
    for (int o = 0; o < H; ++o) p1[o] = sbp1[o];
#pragma unroll
    for (int k = 0; k < H; ++k) {
        const float xk = xg2[k];
#pragma unroll
        for (int o = 0; o < H; ++o) p1[o] = fmaf(xk, sWp1[k * H + o], p1[o]);
    }
#pragma unroll
    for (int k = 0; k < H; ++k) {
        const float xk = x[k];
#pragma unroll
        for (int o = 0; o < H; ++o) p1[o] = fmaf(xk, sWp1[(H + k) * H + o], p1[o]);
    }
#pragma unroll
    for (int o = 0; o < H; ++o) p1[o] = fmaxf(p1[o], 0.0f);

    float p2[H];
#pragma unroll
    for (int o = 0; o < H; ++o) p2[o] = sbp2[o];
#pragma unroll
    for (int k = 0; k < H; ++k) {
        const float xk = p1[k];
#pragma unroll
        for (int o = 0; o < H; ++o) p2[o] = fmaf(xk, sWp2[k * H + o], p2[o]);
    }

    float v = sbv;
#pragma unroll
    for (int k = 0; k < H; ++k) v = fmaf(fmaxf(p2[k], 0.0f), sWv[k], v);

    out[row] = v;
}

// ---------------------------------------------------------------------------
extern "C" void kernel_launch(void* const* d_in, const int* in_sizes, int n_in,
                              void* d_out, int out_size, void* d_ws, size_t ws_size,
                              hipStream_t stream) {
    (void)in_sizes; (void)n_in; (void)out_size; (void)ws_size;

    const float* feat = (const float*)d_in[0];
    const float* adj  = (const float*)d_in[1];
    /* d_in[2] = mask, unused */
    const float* act  = (const float*)d_in[3];
    const float* We1  = (const float*)d_in[4];
    const float* be1  = (const float*)d_in[5];
    const float* We2  = (const float*)d_in[6];
    const float* be2  = (const float*)d_in[7];
    const float* Wg   = (const float*)d_in[8];
    const float* bg   = (const float*)d_in[9];
    const float* Wgd  = (const float*)d_in[10];
    const float* bgd  = (const float*)d_in[11];
    const float* Wp1  = (const float*)d_in[12];
    const float* bp1  = (const float*)d_in[13];
    const float* Wp2  = (const float*)d_in[14];
    const float* bp2  = (const float*)d_in[15];
    const float* Wv   = (const float*)d_in[16];
    const float* bv   = (const float*)d_in[17];

    // workspace layout (16B-aligned chunks)
    char* ws = (char*)d_ws;
    u16*   nbrU = (u16*)ws;                                     // 2 MiB
    u16*   nbrL = (u16*)(ws + (size_t)NN * CAP * 2);            // 2 MiB
    char*  p    = ws + 2 * (size_t)NN * CAP * 2;
    int*   cntU = (int*)p;            p += (size_t)NN * 4;      // 32 KiB
    int*   cntL = (int*)p;            p += (size_t)NN * 4;      // 32 KiB
    float* X    = (float*)p;          p += (size_t)NN * H * 4;  // 1 MiB
    float* T    = (float*)p;                                    // 1 MiB

    float* out = (float*)d_out;

    hipMemsetAsync(cntU, 0, 2 * (size_t)NN * sizeof(int), stream);  // cntU||cntL
    pre_k<<<NENC + NPAIR, 256, 0, stream>>>((const float4*)adj, feat, act,
                                            We1, be1, We2, be2, Wg,
                                            nbrU, nbrL, cntU, cntL, X, T);
    fin_k<<<NN / 64, 64, 0, stream>>>(T, X, nbrU, nbrL, cntU, cntL, bg, Wgd, bgd,
                                      Wp1, bp1, Wp2, bp2, Wv, bv, out);
}

// Round 7
// 422.211 us; speedup vs baseline: 1.0221x; 1.0189x over previous
//
#include <hip/hip_runtime.h>
#include <math.h>

#define NN 8192
#define FD 64
#define AD 8
#define H  32
#define CAP 128   // max neighbors stored per row; deg ~ Poisson(32), P(>128) ~ 0
#define NENC (NN / 256)   // 32 encoder blocks, dispatched FIRST

typedef unsigned short u16;

// LDS layout for the merged kernel (floats)
#define OW1 0                 // (FD+AD)*H = 2304
#define OW2 2304              // H*H = 1024
#define OWG 3328              // H*H = 1024
#define OB1 4352              // H
#define OB2 4384              // H
#define SMEM_FLOATS 4416

// ---------------------------------------------------------------------------
// Kernel 1 (merged): blocks [0, NENC) run the encoder (thread-per-row) so they
// are dispatched first and hide fully under the BW-bound scan; blocks
// [NENC, NENC+NN) scan one adjacency row each (8 upfront 1KB wave-loads,
// LDS-only atomic slot allocation).  Encoder emits UNSCALED T = X@Wg (dinv
// folded into the aggregation fma), so the two paths are independent.
// ---------------------------------------------------------------------------
__global__ __launch_bounds__(256) void pre_k(const float4* __restrict__ adj,
                                             const float* __restrict__ feat,
                                             const float* __restrict__ act,
                                             const float* __restrict__ We1,
                                             const float* __restrict__ be1,
                                             const float* __restrict__ We2,
                                             const float* __restrict__ be2,
                                             const float* __restrict__ Wg,
                                             u16* __restrict__ nbr,
                                             int* __restrict__ cnt,
                                             float* __restrict__ dinv,
                                             float* __restrict__ X,
                                             float* __restrict__ T) {
    __shared__ float smem[SMEM_FLOATS];

    if (blockIdx.x >= NENC) {
        // ----------------- scan path: one adjacency row per block -----------
        int* s_cnt = (int*)smem;
        const int row = blockIdx.x - NENC;
        const float4* arow = adj + (size_t)row * (NN / 4);
        if (threadIdx.x == 0) *s_cnt = 0;
        __syncthreads();

        // issue all 8 loads upfront (8 outstanding 1KB wave-loads)
        float4 v[8];
#pragma unroll
        for (int it = 0; it < 8; ++it) v[it] = arow[it * 256 + threadIdx.x];

        u16* myn = nbr + (size_t)row * CAP;
#pragma unroll
        for (int it = 0; it < 8; ++it) {
            const int base = (it * 256 + threadIdx.x) * 4;
            const int nz0 = (v[it].x != 0.0f), nz1 = (v[it].y != 0.0f);
            const int nz2 = (v[it].z != 0.0f), nz3 = (v[it].w != 0.0f);
            const int local = nz0 + nz1 + nz2 + nz3;
            if (local) {
                int slot = atomicAdd(s_cnt, local);
                if (slot + local <= CAP) {
                    if (nz0) myn[slot++] = (u16)(base);
                    if (nz1) myn[slot++] = (u16)(base + 1);
                    if (nz2) myn[slot++] = (u16)(base + 2);
                    if (nz3) myn[slot++] = (u16)(base + 3);
                }
            }
        }
        __syncthreads();
        if (threadIdx.x == 0) {
            const int c = *s_cnt;
            cnt[row]  = (c < CAP) ? c : CAP;
            dinv[row] = 1.0f / sqrtf((float)c + 1.0f);
        }
    } else {
        // ----------------- encoder path: thread-per-row ---------------------
        for (int i = threadIdx.x; i < (FD + AD) * H; i += 256) smem[OW1 + i] = We1[i];
        for (int i = threadIdx.x; i < H * H; i += 256) {
            smem[OW2 + i] = We2[i];
            smem[OWG + i] = Wg[i];
        }
        if (threadIdx.x < H) {
            smem[OB1 + threadIdx.x] = be1[threadIdx.x];
            smem[OB2 + threadIdx.x] = be2[threadIdx.x];
        }
        __syncthreads();

        const int row = blockIdx.x * 256 + threadIdx.x;

        float in[FD + AD];
        const float4* f4 = (const float4*)(feat + (size_t)row * FD);
#pragma unroll
        for (int i = 0; i < FD / 4; ++i) {
            float4 v = f4[i];
            in[4 * i] = v.x; in[4 * i + 1] = v.y; in[4 * i + 2] = v.z; in[4 * i + 3] = v.w;
        }
        const float4* a4 = (const float4*)(act + (size_t)row * AD);
#pragma unroll
        for (int i = 0; i < AD / 4; ++i) {
            float4 v = a4[i];
            in[FD + 4 * i] = v.x; in[FD + 4 * i + 1] = v.y;
            in[FD + 4 * i + 2] = v.z; in[FD + 4 * i + 3] = v.w;
        }

        float h1[H];
#pragma unroll
        for (int o = 0; o < H; ++o) h1[o] = smem[OB1 + o];
#pragma unroll
        for (int i = 0; i < FD + AD; ++i) {
            const float xi = in[i];
#pragma unroll
            for (int o = 0; o < H; ++o) h1[o] = fmaf(xi, smem[OW1 + i * H + o], h1[o]);
        }
#pragma unroll
        for (int o = 0; o < H; ++o) h1[o] = fmaxf(h1[o], 0.0f);

        float h2[H];
#pragma unroll
        for (int o = 0; o < H; ++o) h2[o] = smem[OB2 + o];
#pragma unroll
        for (int i = 0; i < H; ++i) {
            const float xi = h1[i];
#pragma unroll
            for (int o = 0; o < H; ++o) h2[o] = fmaf(xi, smem[OW2 + i * H + o], h2[o]);
        }
#pragma unroll
        for (int o = 0; o < H; ++o) h2[o] = fmaxf(h2[o], 0.0f);

        float* Xr = X + (size_t)row * H;
#pragma unroll
        for (int o = 0; o < H; o += 4)
            *(float4*)(Xr + o) = make_float4(h2[o], h2[o + 1], h2[o + 2], h2[o + 3]);

        float t[H];
#pragma unroll
        for (int o = 0; o < H; ++o) t[o] = 0.0f;
#pragma unroll
        for (int i = 0; i < H; ++i) {
            const float xi = h2[i];
#pragma unroll
            for (int o = 0; o < H; ++o) t[o] = fmaf(xi, smem[OWG + i * H + o], t[o]);
        }
        float* Tr = T + (size_t)row * H;
#pragma unroll
        for (int o = 0; o < H; o += 4)
            *(float4*)(Tr + o) = make_float4(t[o], t[o + 1], t[o + 2], t[o + 3]);
    }
}

// ---------------------------------------------------------------------------
// Kernel 2: aggregation + heads.  One thread per row, 64-thread blocks
// (128 blocks -> half the CUs with 1 wave each; latency-bound gather).
// acc = T[row]*dinv[row] + sum_j T[j]*dinv[j]
// Edge loop unrolled x4: one ushort4 index load, then 4 dinv + 32 float4
// loads in flight simultaneously to amortize L2 latency.
// ---------------------------------------------------------------------------
__global__ __launch_bounds__(64) void fin_k(const float* __restrict__ T,
                                            const float* __restrict__ X,
                                            const u16* __restrict__ nbr,
                                            const int* __restrict__ cnt,
                                            const float* __restrict__ dinv,
                                            const float* __restrict__ bg,
                                            const float* __restrict__ Wgd,
                                            const float* __restrict__ bgd,
                                            const float* __restrict__ Wp1,
                                            const float* __restrict__ bp1,
                                            const float* __restrict__ Wp2,
                                            const float* __restrict__ bp2,
                                            const float* __restrict__ Wv,
                                            const float* __restrict__ bv,
                                            float* __restrict__ out) {
    __shared__ float sbg[H];
    __shared__ float sWgd[H * H];
    __shared__ float sbgd[H];
    __shared__ float sWp1[2 * H * H];
    __shared__ float sbp1[H];
    __shared__ float sWp2[H * H];
    __shared__ float sbp2[H];
    __shared__ float sWv[H];
    __shared__ float sbv;
    for (int i = threadIdx.x; i < H * H; i += 64) { sWgd[i] = Wgd[i]; sWp2[i] = Wp2[i]; }
    for (int i = threadIdx.x; i < 2 * H * H; i += 64) sWp1[i] = Wp1[i];
    if (threadIdx.x < H) {
        sbg[threadIdx.x]  = bg[threadIdx.x];
        sbgd[threadIdx.x] = bgd[threadIdx.x];
        sbp1[threadIdx.x] = bp1[threadIdx.x];
        sbp2[threadIdx.x] = bp2[threadIdx.x];
        sWv[threadIdx.x]  = Wv[threadIdx.x];
    }
    if (threadIdx.x == 0) sbv = bv[0];
    __syncthreads();

    const int row = blockIdx.x * 64 + threadIdx.x;
    const float di = dinv[row];

    float acc[H];
    const float4* Tr = (const float4*)(T + (size_t)row * H);
#pragma unroll
    for (int q = 0; q < H / 4; ++q) {
        float4 v = Tr[q];
        acc[4 * q]     = v.x * di; acc[4 * q + 1] = v.y * di;
        acc[4 * q + 2] = v.z * di; acc[4 * q + 3] = v.w * di;
    }

    const int n = cnt[row];
    const u16* myn = nbr + (size_t)row * CAP;
    int e = 0;
    for (; e + 4 <= n; e += 4) {
        const ushort4 ii = *(const ushort4*)(myn + e);   // 8B-aligned (e%4==0)
        const int j0 = ii.x, j1 = ii.y, j2 = ii.z, j3 = ii.w;
        const float d0 = dinv[j0], d1 = dinv[j1], d2 = dinv[j2], d3 = dinv[j3];
        const float4* T0 = (const float4*)(T + (size_t)j0 * H);
        const float4* T1 = (const float4*)(T + (size_t)j1 * H);
        const float4* T2 = (const float4*)(T + (size_t)j2 * H);
        const float4* T3 = (const float4*)(T + (size_t)j3 * H);
#pragma unroll
        for (int q = 0; q < H / 4; ++q) {
            const float4 a = T0[q], b = T1[q], c = T2[q], d = T3[q];
            acc[4 * q]     = fmaf(a.x, d0, acc[4 * q]);
            acc[4 * q + 1] = fmaf(a.y, d0, acc[4 * q + 1]);
            acc[4 * q + 2] = fmaf(a.z, d0, acc[4 * q + 2]);
            acc[4 * q + 3] = fmaf(a.w, d0, acc[4 * q + 3]);
            acc[4 * q]     = fmaf(b.x, d1, acc[4 * q]);
            acc[4 * q + 1] = fmaf(b.y, d1, acc[4 * q + 1]);
            acc[4 * q + 2] = fmaf(b.z, d1, acc[4 * q + 2]);
            acc[4 * q + 3] = fmaf(b.w, d1, acc[4 * q + 3]);
            acc[4 * q]     = fmaf(c.x, d2, acc[4 * q]);
            acc[4 * q + 1] = fmaf(c.y, d2, acc[4 * q + 1]);
            acc[4 * q + 2] = fmaf(c.z, d2, acc[4 * q + 2]);
            acc[4 * q + 3] = fmaf(c.w, d2, acc[4 * q + 3]);
            acc[4 * q]     = fmaf(d.x, d3, acc[4 * q]);
            acc[4 * q + 1] = fmaf(d.y, d3, acc[4 * q + 1]);
            acc[4 * q + 2] = fmaf(d.z, d3, acc[4 * q + 2]);
            acc[4 * q + 3] = fmaf(d.w, d3, acc[4 * q + 3]);
        }
    }
    for (; e < n; ++e) {
        const int j = myn[e];
        const float dj = dinv[j];
        const float4* Tj = (const float4*)(T + (size_t)j * H);
#pragma unroll
        for (int q = 0; q < H / 4; ++q) {
            const float4 v = Tj[q];
            acc[4 * q]     = fmaf(v.x, dj, acc[4 * q]);
            acc[4 * q + 1] = fmaf(v.y, dj, acc[4 * q + 1]);
            acc[4 * q + 2] = fmaf(v.z, dj, acc[4 * q + 2]);
            acc[4 * q + 3] = fmaf(v.w, dj, acc[4 * q + 3]);
        }
    }

    float xg[H];
#pragma unroll
    for (int k = 0; k < H; ++k) xg[k] = fmaxf(fmaf(acc[k], di, sbg[k]), 0.0f);

    float xg2[H];
#pragma unroll
    for (int o = 0; o < H; ++o) xg2[o] = sbgd[o];
#pragma unroll
    for (int k = 0; k < H; ++k) {
        const float xk = xg[k];
#pragma unroll
        for (int o = 0; o < H; ++o) xg2[o] = fmaf(xk, sWgd[k * H + o], xg2[o]);
    }
#pragma unroll
    for (int o = 0; o < H; ++o) xg2[o] = fmaxf(xg2[o], 0.0f);

    float x[H];
    const float4* Xr = (const float4*)(X + (size_t)row * H);
#pragma unroll
    for (int q = 0; q < H / 4; ++q) {
        float4 v = Xr[q];
        x[4 * q] = v.x; x[4 * q + 1] = v.y; x[4 * q + 2] = v.z; x[4 * q + 3] = v.w;
    }

    float p1[H];
#pragma unroll
    for (int o = 0; o < H; ++o) p1[o] = sbp1[o];
#pragma unroll
    for (int k = 0; k < H; ++k) {
        const float xk = xg2[k];
#pragma unroll
        for (int o = 0; o < H; ++o) p1[o] = fmaf(xk, sWp1[k * H + o], p1[o]);
    }
#pragma unroll
    for (int k = 0; k < H; ++k) {
        const float xk = x[k];
#pragma unroll
        for (int o = 0; o < H; ++o) p1[o] = fmaf(xk, sWp1[(H + k) * H + o], p1[o]);
    }
#pragma unroll
    for (int o = 0; o < H; ++o) p1[o] = fmaxf(p1[o], 0.0f);

    float p2[H];
#pragma unroll
    for (int o = 0; o < H; ++o) p2[o] = sbp2[o];
#pragma unroll
    for (int k = 0; k < H; ++k) {
        const float xk = p1[k];
#pragma unroll
        for (int o = 0; o < H; ++o) p2[o] = fmaf(xk, sWp2[k * H + o], p2[o]);
    }

    float v = sbv;
#pragma unroll
    for (int k = 0; k < H; ++k) v = fmaf(fmaxf(p2[k], 0.0f), sWv[k], v);

    out[row] = v;
}

// ---------------------------------------------------------------------------
extern "C" void kernel_launch(void* const* d_in, const int* in_sizes, int n_in,
                              void* d_out, int out_size, void* d_ws, size_t ws_size,
                              hipStream_t stream) {
    (void)in_sizes; (void)n_in; (void)out_size; (void)ws_size;

    const float* feat = (const float*)d_in[0];
    const float* adj  = (const float*)d_in[1];
    /* d_in[2] = mask, unused */
    const float* act  = (const float*)d_in[3];
    const float* We1  = (const float*)d_in[4];
    const float* be1  = (const float*)d_in[5];
    const float* We2  = (const float*)d_in[6];
    const float* be2  = (const float*)d_in[7];
    const float* Wg   = (const float*)d_in[8];
    const float* bg   = (const float*)d_in[9];
    const float* Wgd  = (const float*)d_in[10];
    const float* bgd  = (const float*)d_in[11];
    const float* Wp1  = (const float*)d_in[12];
    const float* bp1  = (const float*)d_in[13];
    const float* Wp2  = (const float*)d_in[14];
    const float* bp2  = (const float*)d_in[15];
    const float* Wv   = (const float*)d_in[16];
    const float* bv   = (const float*)d_in[17];

    // workspace layout (16B-aligned chunks)
    char* ws = (char*)d_ws;
    u16*   nbr  = (u16*)ws;                                    // 8192*128*2  = 2 MiB
    char*  p    = ws + (size_t)NN * CAP * sizeof(u16);
    int*   cnt  = (int*)p;            p += (size_t)NN * 4;     // 32 KiB
    float* dinv = (float*)p;          p += (size_t)NN * 4;     // 32 KiB
    float* X    = (float*)p;          p += (size_t)NN * H * 4; // 1 MiB
    float* T    = (float*)p;                                   // 1 MiB (unscaled X@Wg)

    float* out = (float*)d_out;

    pre_k<<<NENC + NN, 256, 0, stream>>>((const float4*)adj, feat, act,
                                         We1, be1, We2, be2, Wg,
                                         nbr, cnt, dinv, X, T);
    fin_k<<<NN / 64, 64, 0, stream>>>(T, X, nbr, cnt, dinv, bg, Wgd, bgd,
                                      Wp1, bp1, Wp2, bp2, Wv, bv, out);
}